// Round 1
// baseline (699.980 us; speedup 1.0000x reference)
//
#include <hip/hip_runtime.h>
#include <cmath>

static constexpr int NN = 100000;   // nodes
static constexpr int NE = 1600000;  // edges

// ---------------------------------------------------------------------------
// Dual matmul: out_r = in @ Wrel, out_o = in @ Wroot.  in:[N,K], W:[K,32].
// 8 nodes per 256-thread block; 32 lanes per node, lane j owns output col j.
// Weights staged in LDS (K*32*2*4 B <= 16 KiB).
// ---------------------------------------------------------------------------
template <int K>
__global__ void __launch_bounds__(256) dual_matmul_k(
    const float* __restrict__ in, const float* __restrict__ Wrel,
    const float* __restrict__ Wroot, float* __restrict__ out_r,
    float* __restrict__ out_o)
{
    __shared__ float sWr[K * 32];
    __shared__ float sWo[K * 32];
    for (int i = threadIdx.x; i < K * 32; i += 256) {
        sWr[i] = Wrel[i];
        sWo[i] = Wroot[i];
    }
    __syncthreads();
    int n = blockIdx.x * 8 + (threadIdx.x >> 5);
    int j = threadIdx.x & 31;
    if (n >= NN) return;
    const float* row = in + (size_t)n * K;
    float ar = 0.f, ao = 0.f;
#pragma unroll
    for (int k = 0; k < K; ++k) {
        float xv = row[k];  // broadcast within the 32-lane group
        ar = fmaf(xv, sWr[k * 32 + j], ar);
        ao = fmaf(xv, sWo[k * 32 + j], ao);
    }
    out_r[n * 32 + j] = ar;
    out_o[n * 32 + j] = ao;
}

// ---------------------------------------------------------------------------
// 32-wide edge scatter: agg[dst[e]][f] += srcfeat[src[e]][f] * ew[e]
// One thread per (edge, feature). Lanes f=0..31 are coalesced on both the
// gather row and the atomic destination row.
// ---------------------------------------------------------------------------
__global__ void __launch_bounds__(256) scatter32_k(
    const float* __restrict__ srcfeat, const int* __restrict__ src,
    const int* __restrict__ dst, const float* __restrict__ ew,
    float* __restrict__ agg)
{
    unsigned idx = blockIdx.x * 256u + threadIdx.x;
    if (idx >= (unsigned)NE * 32u) return;
    int e = idx >> 5;
    int f = idx & 31;
    int s = src[e];
    int d = dst[e];
    float v = srcfeat[(size_t)s * 32 + f] * ew[e];
    atomicAdd(agg + (size_t)d * 32 + f, v);
}

// h = relu(agg + b[j] + root)
__global__ void __launch_bounds__(256) bias_relu_k(
    const float* __restrict__ agg, const float* __restrict__ root,
    const float* __restrict__ b, float* __restrict__ out)
{
    unsigned idx = blockIdx.x * 256u + threadIdx.x;
    if (idx >= (unsigned)NN * 32u) return;
    float v = agg[idx] + b[idx & 31] + root[idx];
    out[idx] = v > 0.f ? v : 0.f;
}

// ---------------------------------------------------------------------------
// Fused layer-2 epilogue + p/v head projections.
// h2 = relu(agg2 + bh + ho); then 4 dot products with [32]-vectors via
// width-32 shuffle reduction. Lane 0 of each node group writes:
//   pr[n] = h2 . Wp_rel,  vr[n] = h2 . Wv_rel
//   pbase[n] = h2 . Wp_root + bp,  vbase[n] = h2 . Wv_root + bv
// ---------------------------------------------------------------------------
__global__ void __launch_bounds__(256) heads_k(
    const float* __restrict__ agg2, const float* __restrict__ ho,
    const float* __restrict__ bh, const float* __restrict__ Wp_rel,
    const float* __restrict__ Wp_root, const float* __restrict__ bp,
    const float* __restrict__ Wv_rel, const float* __restrict__ Wv_root,
    const float* __restrict__ bv, float* __restrict__ pr,
    float* __restrict__ vr, float* __restrict__ pbase,
    float* __restrict__ vbase)
{
    unsigned gid = blockIdx.x * 256u + threadIdx.x;
    int n = gid >> 5;
    int j = gid & 31;
    if (n >= NN) return;
    float hv = agg2[gid] + bh[j] + ho[gid];
    hv = hv > 0.f ? hv : 0.f;
    float prv = hv * Wp_rel[j];
    float pov = hv * Wp_root[j];
    float vrv = hv * Wv_rel[j];
    float vov = hv * Wv_root[j];
#pragma unroll
    for (int m = 16; m; m >>= 1) {
        prv += __shfl_xor(prv, m, 32);
        pov += __shfl_xor(pov, m, 32);
        vrv += __shfl_xor(vrv, m, 32);
        vov += __shfl_xor(vov, m, 32);
    }
    if (j == 0) {
        pr[n] = prv;
        vr[n] = vrv;
        pbase[n] = pov + bp[0];
        vbase[n] = vov + bv[0];
    }
}

// Scalar head scatter + legal-move mask (one thread per edge).
__global__ void __launch_bounds__(256) scatter_heads_k(
    const int* __restrict__ src, const int* __restrict__ dst,
    const float* __restrict__ ew, const int* __restrict__ curp,
    const float* __restrict__ pr, const float* __restrict__ vr,
    float* __restrict__ aggp, float* __restrict__ aggv,
    float* __restrict__ maskb)
{
    unsigned e = blockIdx.x * 256u + threadIdx.x;
    if (e >= (unsigned)NE) return;
    int s = src[e];
    int d = dst[e];
    float w = ew[e];
    atomicAdd(aggp + d, pr[s] * w);
    atomicAdd(aggv + d, vr[s] * w);
    if (s == curp[0]) maskb[d] = 1.0f;  // racing stores of identical value: fine
}

// p = aggp + pbase; v = aggv + vbase; apply mask; emit v_m; pm with -inf;
// per-block max of pm -> partials.
__global__ void __launch_bounds__(256) finalize_k(
    const float* __restrict__ aggp, const float* __restrict__ aggv,
    const float* __restrict__ pbase, const float* __restrict__ vbase,
    const float* __restrict__ maskb, float* __restrict__ pm,
    float* __restrict__ out_v, float* __restrict__ partials)
{
    int n = blockIdx.x * 256 + threadIdx.x;
    float pmv = -INFINITY;
    if (n < NN) {
        float m = maskb[n];
        float p = aggp[n] + pbase[n];
        float v = aggv[n] + vbase[n];
        float pm0 = m * p;
        pmv = (pm0 == 0.f) ? -INFINITY : pm0;  // matches jnp.where(p_m==0,-inf,p_m)
        pm[n] = pmv;
        out_v[n] = m * v;
    }
    __shared__ float smax[4];
    float wm = pmv;
#pragma unroll
    for (int k = 32; k; k >>= 1) wm = fmaxf(wm, __shfl_xor(wm, k, 64));
    if ((threadIdx.x & 63) == 0) smax[threadIdx.x >> 6] = wm;
    __syncthreads();
    if (threadIdx.x == 0) {
        float bm = fmaxf(fmaxf(smax[0], smax[1]), fmaxf(smax[2], smax[3]));
        partials[blockIdx.x] = bm;
    }
}

// Single-block reduction of per-block maxes; also zeroes the sum slot.
__global__ void __launch_bounds__(256) reduce_max_k(
    const float* __restrict__ partials, int np, float* __restrict__ scal)
{
    float m = -INFINITY;
    for (int i = threadIdx.x; i < np; i += 256) m = fmaxf(m, partials[i]);
    __shared__ float s[4];
#pragma unroll
    for (int k = 32; k; k >>= 1) m = fmaxf(m, __shfl_xor(m, k, 64));
    if ((threadIdx.x & 63) == 0) s[threadIdx.x >> 6] = m;
    __syncthreads();
    if (threadIdx.x == 0) {
        scal[0] = fmaxf(fmaxf(s[0], s[1]), fmaxf(s[2], s[3]));
        scal[1] = 0.f;  // sum accumulator init
    }
}

// ev = exp(pm - M) (0 for -inf); block-sum -> atomicAdd(scal[1])
__global__ void __launch_bounds__(256) expsum_k(
    const float* __restrict__ pm, float* __restrict__ scal,
    float* __restrict__ ev)
{
    int n = blockIdx.x * 256 + threadIdx.x;
    float e = 0.f;
    if (n < NN) {
        float x = pm[n];
        e = (x == -INFINITY) ? 0.f : expf(x - scal[0]);
        ev[n] = e;
    }
    __shared__ float s[4];
    float ws = e;
#pragma unroll
    for (int k = 32; k; k >>= 1) ws += __shfl_xor(ws, k, 64);
    if ((threadIdx.x & 63) == 0) s[threadIdx.x >> 6] = ws;
    __syncthreads();
    if (threadIdx.x == 0) atomicAdd(scal + 1, s[0] + s[1] + s[2] + s[3]);
}

__global__ void __launch_bounds__(256) normalize_k(
    const float* __restrict__ ev, const float* __restrict__ scal,
    float* __restrict__ out)
{
    int n = blockIdx.x * 256 + threadIdx.x;
    if (n < NN) out[n] = ev[n] / scal[1];
}

// ---------------------------------------------------------------------------
extern "C" void kernel_launch(void* const* d_in, const int* in_sizes, int n_in,
                              void* d_out, int out_size, void* d_ws,
                              size_t ws_size, hipStream_t stream)
{
    const float* x        = (const float*)d_in[0];
    const int*   ei       = (const int*)d_in[1];   // [2,E] row-major
    const float* ew       = (const float*)d_in[2];
    const int*   cur      = (const int*)d_in[3];
    const float* Win_rel  = (const float*)d_in[4];
    const float* bin_rel  = (const float*)d_in[5];
    const float* Win_root = (const float*)d_in[6];
    const float* Wh_rel   = (const float*)d_in[7];
    const float* bh_rel   = (const float*)d_in[8];
    const float* Wh_root  = (const float*)d_in[9];
    const float* Wp_rel   = (const float*)d_in[10];
    const float* bp       = (const float*)d_in[11];
    const float* Wp_root  = (const float*)d_in[12];
    const float* Wv_rel   = (const float*)d_in[13];
    const float* bv       = (const float*)d_in[14];
    const float* Wv_root  = (const float*)d_in[15];

    const int* srcA = ei;
    const int* dstA = ei + NE;

    // Workspace layout (floats). Peak need: 4 * N*32 * 4 B = 51.2 MB.
    float* ws = (float*)d_ws;
    const size_t NW = (size_t)NN * 32;
    float* A = ws;            // xr / hr
    float* B = ws + NW;       // xo / ho
    float* C = ws + 2 * NW;   // agg1 / agg2
    float* D = ws + 3 * NW;   // h1, later subdivided:
    float* pr     = D;
    float* vr     = D + 1 * (size_t)NN;
    float* pbase  = D + 2 * (size_t)NN;
    float* vbase  = D + 3 * (size_t)NN;
    float* aggp   = D + 4 * (size_t)NN;
    float* aggv   = D + 5 * (size_t)NN;
    float* maskb  = D + 6 * (size_t)NN;
    float* pm     = D + 7 * (size_t)NN;
    float* evbuf  = D + 8 * (size_t)NN;
    float* parts  = D + 9 * (size_t)NN;   // 391 entries
    float* scal   = parts + 512;          // [0]=max, [1]=sum

    float* out_p = (float*)d_out;
    float* out_v = out_p + NN;

    const int NB_N   = (NN + 255) / 256;        // 391
    const int NB_NW  = (int)((NW + 255) / 256); // 12500
    const int NB_EW  = (int)(((size_t)NE * 32 + 255) / 256);
    const int NB_E   = (NE + 255) / 256;
    const int NB_NOD = (NN + 7) / 8;

    // Layer 1: A = x@Win_rel, B = x@Win_root (K=64)
    dual_matmul_k<64><<<NB_NOD, 256, 0, stream>>>(x, Win_rel, Win_root, A, B);
    hipMemsetAsync(C, 0, NW * sizeof(float), stream);
    scatter32_k<<<NB_EW, 256, 0, stream>>>(A, srcA, dstA, ew, C);
    bias_relu_k<<<NB_NW, 256, 0, stream>>>(C, B, bin_rel, D);  // D = h1

    // Layer 2: A = h1@Wh_rel, B = h1@Wh_root (K=32)
    dual_matmul_k<32><<<NB_NOD, 256, 0, stream>>>(D, Wh_rel, Wh_root, A, B);
    hipMemsetAsync(C, 0, NW * sizeof(float), stream);
    scatter32_k<<<NB_EW, 256, 0, stream>>>(A, srcA, dstA, ew, C);

    // Fused h2 + head projections (h1 in D no longer needed -> reuse D)
    heads_k<<<NB_NW, 256, 0, stream>>>(C, B, bh_rel, Wp_rel, Wp_root, bp,
                                       Wv_rel, Wv_root, bv, pr, vr, pbase,
                                       vbase);
    hipMemsetAsync(aggp, 0, 3 * (size_t)NN * sizeof(float), stream);
    scatter_heads_k<<<NB_E, 256, 0, stream>>>(srcA, dstA, ew, cur, pr, vr,
                                              aggp, aggv, maskb);

    // Mask, v output, masked-softmax over p
    finalize_k<<<NB_N, 256, 0, stream>>>(aggp, aggv, pbase, vbase, maskb, pm,
                                         out_v, parts);
    reduce_max_k<<<1, 256, 0, stream>>>(parts, NB_N, scal);
    expsum_k<<<NB_N, 256, 0, stream>>>(pm, scal, evbuf);
    normalize_k<<<NB_N, 256, 0, stream>>>(evbuf, scal, out_p);
}

// Round 2
// 496.766 us; speedup vs baseline: 1.4091x; 1.4091x over previous
//
#include <hip/hip_runtime.h>
#include <cmath>

static constexpr int NN = 100000;   // nodes
static constexpr int NE = 1600000;  // edges
static const size_t NW = (size_t)NN * 32;

// ---------------------------------------------------------------------------
// CSR build: histogram of dst, exclusive scan, fill packed (src, weight).
// ---------------------------------------------------------------------------
__global__ void __launch_bounds__(256) hist_k(const int* __restrict__ dst,
                                              int* __restrict__ deg)
{
    unsigned e = blockIdx.x * 256u + threadIdx.x;
    if (e < (unsigned)NE) atomicAdd(deg + dst[e], 1);
}

__global__ void __launch_bounds__(256) block_sum_k(const int* __restrict__ deg,
                                                   int* __restrict__ bsum)
{
    int n = blockIdx.x * 256 + threadIdx.x;
    int d = (n < NN) ? deg[n] : 0;
#pragma unroll
    for (int k = 32; k; k >>= 1) d += __shfl_xor(d, k, 64);
    __shared__ int s[4];
    if ((threadIdx.x & 63) == 0) s[threadIdx.x >> 6] = d;
    __syncthreads();
    if (threadIdx.x == 0) bsum[blockIdx.x] = s[0] + s[1] + s[2] + s[3];
}

// one block of 512 threads: exclusive scan of up to 512 block sums
__global__ void __launch_bounds__(512) scan_bsum_k(const int* __restrict__ bsum,
                                                   int np, int* __restrict__ ebase)
{
    __shared__ int tmp[512];
    int t = threadIdx.x;
    int v = (t < np) ? bsum[t] : 0;
    tmp[t] = v;
    __syncthreads();
    for (int s = 1; s < 512; s <<= 1) {
        int x = tmp[t];
        int add = (t >= s) ? tmp[t - s] : 0;
        __syncthreads();
        tmp[t] = x + add;
        __syncthreads();
    }
    if (t < np) ebase[t] = tmp[t] - v;
}

__global__ void __launch_bounds__(256) scan_write_k(const int* __restrict__ deg,
                                                    const int* __restrict__ ebase,
                                                    int* __restrict__ off,
                                                    int* __restrict__ cursor)
{
    __shared__ int tmp[256];
    int t = threadIdx.x;
    int n = blockIdx.x * 256 + t;
    int d = (n < NN) ? deg[n] : 0;
    tmp[t] = d;
    __syncthreads();
    for (int s = 1; s < 256; s <<= 1) {
        int x = tmp[t];
        int add = (t >= s) ? tmp[t - s] : 0;
        __syncthreads();
        tmp[t] = x + add;
        __syncthreads();
    }
    int excl = tmp[t] - d;
    if (n < NN) {
        int base = ebase[blockIdx.x] + excl;
        off[n] = base;
        cursor[n] = base;
    }
}

__global__ void __launch_bounds__(256) fill_k(const int* __restrict__ src,
                                              const int* __restrict__ dst,
                                              const float* __restrict__ ew,
                                              int* __restrict__ cursor,
                                              int2* __restrict__ csr)
{
    unsigned e = blockIdx.x * 256u + threadIdx.x;
    if (e >= (unsigned)NE) return;
    int d = dst[e];
    int pos = atomicAdd(cursor + d, 1);
    int2 pk;
    pk.x = src[e];
    pk.y = __float_as_int(ew[e]);
    csr[pos] = pk;
}

// ---------------------------------------------------------------------------
// proj = in @ W  (W: [K,32] in LDS). 8 nodes/block, lane j owns col j.
// ---------------------------------------------------------------------------
template <int K>
__global__ void __launch_bounds__(256) matmul_k(const float* __restrict__ in,
                                                const float* __restrict__ W,
                                                float* __restrict__ out)
{
    __shared__ float sW[K * 32];
    for (int i = threadIdx.x; i < K * 32; i += 256) sW[i] = W[i];
    __syncthreads();
    int n = blockIdx.x * 8 + (threadIdx.x >> 5);
    int j = threadIdx.x & 31;
    const float* row = in + (size_t)n * K;
    float acc = 0.f;
#pragma unroll
    for (int k = 0; k < K; ++k) acc = fmaf(row[k], sW[k * 32 + j], acc);
    out[(size_t)n * 32 + j] = acc;
}

// ---------------------------------------------------------------------------
// Gather-aggregate layer: h_out[n] = relu( sum_{e in CSR(n)} w_e*proj[src_e]
//                                          + bias + x_row(n)@Wroot )
// Root matmul recomputed inline from LDS weights (saves a 25.6 MB roundtrip).
// ---------------------------------------------------------------------------
template <int K>
__global__ void __launch_bounds__(256) agg_root_relu_k(
    const float* __restrict__ proj, const float* __restrict__ xin,
    const float* __restrict__ Wroot, const float* __restrict__ bias,
    const int2* __restrict__ csr, const int* __restrict__ off,
    const int* __restrict__ deg, float* __restrict__ hout)
{
    __shared__ float sW[K * 32];
    for (int i = threadIdx.x; i < K * 32; i += 256) sW[i] = Wroot[i];
    __syncthreads();
    int n = blockIdx.x * 8 + (threadIdx.x >> 5);
    int j = threadIdx.x & 31;
    int st = off[n], dg = deg[n];
    float acc = 0.f;
    int i = 0;
    for (; i + 3 < dg; i += 4) {
        int2 e0 = csr[st + i], e1 = csr[st + i + 1];
        int2 e2 = csr[st + i + 2], e3 = csr[st + i + 3];
        float a0 = proj[(size_t)e0.x * 32 + j];
        float a1 = proj[(size_t)e1.x * 32 + j];
        float a2 = proj[(size_t)e2.x * 32 + j];
        float a3 = proj[(size_t)e3.x * 32 + j];
        acc = fmaf(a0, __int_as_float(e0.y), acc);
        acc = fmaf(a1, __int_as_float(e1.y), acc);
        acc = fmaf(a2, __int_as_float(e2.y), acc);
        acc = fmaf(a3, __int_as_float(e3.y), acc);
    }
    for (; i < dg; ++i) {
        int2 e0 = csr[st + i];
        acc = fmaf(proj[(size_t)e0.x * 32 + j], __int_as_float(e0.y), acc);
    }
    const float* row = xin + (size_t)n * K;
    float r = 0.f;
#pragma unroll
    for (int k = 0; k < K; ++k) r = fmaf(row[k], sW[k * 32 + j], r);
    float v = acc + bias[j] + r;
    hout[(size_t)n * 32 + j] = v > 0.f ? v : 0.f;
}

// ---------------------------------------------------------------------------
// Layer-2 aggregate + inline root + ReLU + all four OUT=1 head projections.
// Writes pv[n]={h2.Wp_rel, h2.Wv_rel}, pbase[n]=h2.Wp_root+bp, vbase likewise.
// ---------------------------------------------------------------------------
__global__ void __launch_bounds__(256) agg2_heads_k(
    const float* __restrict__ proj, const float* __restrict__ h1,
    const float* __restrict__ Wroot, const float* __restrict__ bias,
    const float* __restrict__ Wp_rel, const float* __restrict__ Wp_root,
    const float* __restrict__ bp, const float* __restrict__ Wv_rel,
    const float* __restrict__ Wv_root, const float* __restrict__ bv,
    const int2* __restrict__ csr, const int* __restrict__ off,
    const int* __restrict__ deg, float2* __restrict__ pv,
    float* __restrict__ pbase, float* __restrict__ vbase)
{
    __shared__ float sW[32 * 32];
    __shared__ float sHead[4 * 32];
    for (int i = threadIdx.x; i < 32 * 32; i += 256) sW[i] = Wroot[i];
    if (threadIdx.x < 32) {
        sHead[threadIdx.x] = Wp_rel[threadIdx.x];
        sHead[32 + threadIdx.x] = Wp_root[threadIdx.x];
        sHead[64 + threadIdx.x] = Wv_rel[threadIdx.x];
        sHead[96 + threadIdx.x] = Wv_root[threadIdx.x];
    }
    __syncthreads();
    int n = blockIdx.x * 8 + (threadIdx.x >> 5);
    int j = threadIdx.x & 31;
    int st = off[n], dg = deg[n];
    float acc = 0.f;
    int i = 0;
    for (; i + 3 < dg; i += 4) {
        int2 e0 = csr[st + i], e1 = csr[st + i + 1];
        int2 e2 = csr[st + i + 2], e3 = csr[st + i + 3];
        float a0 = proj[(size_t)e0.x * 32 + j];
        float a1 = proj[(size_t)e1.x * 32 + j];
        float a2 = proj[(size_t)e2.x * 32 + j];
        float a3 = proj[(size_t)e3.x * 32 + j];
        acc = fmaf(a0, __int_as_float(e0.y), acc);
        acc = fmaf(a1, __int_as_float(e1.y), acc);
        acc = fmaf(a2, __int_as_float(e2.y), acc);
        acc = fmaf(a3, __int_as_float(e3.y), acc);
    }
    for (; i < dg; ++i) {
        int2 e0 = csr[st + i];
        acc = fmaf(proj[(size_t)e0.x * 32 + j], __int_as_float(e0.y), acc);
    }
    const float* row = h1 + (size_t)n * 32;
    float r = 0.f;
#pragma unroll
    for (int k = 0; k < 32; ++k) r = fmaf(row[k], sW[k * 32 + j], r);
    float hv = acc + bias[j] + r;
    hv = hv > 0.f ? hv : 0.f;
    float prv = hv * sHead[j];
    float pov = hv * sHead[32 + j];
    float vrv = hv * sHead[64 + j];
    float vov = hv * sHead[96 + j];
#pragma unroll
    for (int m = 16; m; m >>= 1) {
        prv += __shfl_xor(prv, m, 32);
        pov += __shfl_xor(pov, m, 32);
        vrv += __shfl_xor(vrv, m, 32);
        vov += __shfl_xor(vov, m, 32);
    }
    if (j == 0) {
        pv[n] = make_float2(prv, vrv);
        pbase[n] = pov + bp[0];
        vbase[n] = vov + bv[0];
    }
}

// ---------------------------------------------------------------------------
// Per-node head aggregation + legal-move mask + masked outputs + block max.
// mask[n] = any in-edge with src == current_node  (== reference's scatter>0)
// ---------------------------------------------------------------------------
__global__ void __launch_bounds__(256) heads_final_k(
    const float2* __restrict__ pv, const float* __restrict__ pbase,
    const float* __restrict__ vbase, const int2* __restrict__ csr,
    const int* __restrict__ off, const int* __restrict__ deg,
    const int* __restrict__ curp, float* __restrict__ pm,
    float* __restrict__ out_v, float* __restrict__ partials)
{
    int n = blockIdx.x * 256 + threadIdx.x;
    int cur = curp[0];
    float pmv = -INFINITY;
    if (n < NN) {
        int st = off[n], dg = deg[n];
        float pa = 0.f, va = 0.f, m = 0.f;
        for (int i = 0; i < dg; ++i) {
            int2 e = csr[st + i];
            float2 t = pv[e.x];
            float w = __int_as_float(e.y);
            pa = fmaf(t.x, w, pa);
            va = fmaf(t.y, w, va);
            if (e.x == cur) m = 1.f;
        }
        float p = pa + pbase[n];
        float v = va + vbase[n];
        float pm0 = m * p;
        pmv = (pm0 == 0.f) ? -INFINITY : pm0;  // jnp.where(p_m==0, -inf, p_m)
        pm[n] = pmv;
        out_v[n] = m * v;
    }
    __shared__ float smax[4];
    float wm = pmv;
#pragma unroll
    for (int k = 32; k; k >>= 1) wm = fmaxf(wm, __shfl_xor(wm, k, 64));
    if ((threadIdx.x & 63) == 0) smax[threadIdx.x >> 6] = wm;
    __syncthreads();
    if (threadIdx.x == 0)
        partials[blockIdx.x] = fmaxf(fmaxf(smax[0], smax[1]), fmaxf(smax[2], smax[3]));
}

__global__ void __launch_bounds__(256) reduce_max_k(
    const float* __restrict__ partials, int np, float* __restrict__ scal)
{
    float m = -INFINITY;
    for (int i = threadIdx.x; i < np; i += 256) m = fmaxf(m, partials[i]);
    __shared__ float s[4];
#pragma unroll
    for (int k = 32; k; k >>= 1) m = fmaxf(m, __shfl_xor(m, k, 64));
    if ((threadIdx.x & 63) == 0) s[threadIdx.x >> 6] = m;
    __syncthreads();
    if (threadIdx.x == 0) {
        scal[0] = fmaxf(fmaxf(s[0], s[1]), fmaxf(s[2], s[3]));
        scal[1] = 0.f;
    }
}

__global__ void __launch_bounds__(256) expsum_k(const float* __restrict__ pm,
                                                float* __restrict__ scal,
                                                float* __restrict__ ev)
{
    int n = blockIdx.x * 256 + threadIdx.x;
    float e = 0.f;
    if (n < NN) {
        float x = pm[n];
        e = (x == -INFINITY) ? 0.f : expf(x - scal[0]);
        ev[n] = e;
    }
    __shared__ float s[4];
    float ws = e;
#pragma unroll
    for (int k = 32; k; k >>= 1) ws += __shfl_xor(ws, k, 64);
    if ((threadIdx.x & 63) == 0) s[threadIdx.x >> 6] = ws;
    __syncthreads();
    if (threadIdx.x == 0) atomicAdd(scal + 1, s[0] + s[1] + s[2] + s[3]);
}

__global__ void __launch_bounds__(256) normalize_k(const float* __restrict__ ev,
                                                   const float* __restrict__ scal,
                                                   float* __restrict__ out)
{
    int n = blockIdx.x * 256 + threadIdx.x;
    if (n < NN) out[n] = ev[n] / scal[1];
}

// ---------------------------------------------------------------------------
extern "C" void kernel_launch(void* const* d_in, const int* in_sizes, int n_in,
                              void* d_out, int out_size, void* d_ws,
                              size_t ws_size, hipStream_t stream)
{
    const float* x        = (const float*)d_in[0];
    const int*   ei       = (const int*)d_in[1];   // [2,E] row-major
    const float* ew       = (const float*)d_in[2];
    const int*   cur      = (const int*)d_in[3];
    const float* Win_rel  = (const float*)d_in[4];
    const float* bin_rel  = (const float*)d_in[5];
    const float* Win_root = (const float*)d_in[6];
    const float* Wh_rel   = (const float*)d_in[7];
    const float* bh_rel   = (const float*)d_in[8];
    const float* Wh_root  = (const float*)d_in[9];
    const float* Wp_rel   = (const float*)d_in[10];
    const float* bp       = (const float*)d_in[11];
    const float* Wp_root  = (const float*)d_in[12];
    const float* Wv_rel   = (const float*)d_in[13];
    const float* bv       = (const float*)d_in[14];
    const float* Wv_root  = (const float*)d_in[15];

    const int* srcA = ei;
    const int* dstA = ei + NE;

    // Workspace layout (~41.2 MB; round-1 layout proved ws >= 42 MB works)
    char* w8 = (char*)d_ws;
    int2* csr   = (int2*)w8;                 // 12.8 MB
    int* deg    = (int*)(csr + NE);          // 400 KB
    int* off    = deg + NN;
    int* cursor = off + NN;
    int* bsum   = cursor + NN;               // 512 ints
    int* ebase  = bsum + 512;                // 512 ints
    float* A    = (float*)(ebase + 512);     // 12.8 MB  (proj1 / proj2)
    float* H    = A + NW;                    // 12.8 MB  (h1)
    float2* pv  = (float2*)(H + NW);         // 800 KB
    float* pbase = (float*)(pv + NN);        // 400 KB
    float* vbase = pbase + NN;               // 400 KB
    // aliases into A (free after agg2_heads_k):
    float* pm    = A;
    float* ev    = A + NN;
    float* parts = A + 2 * (size_t)NN;       // 391
    float* scal  = parts + 512;

    float* out_p = (float*)d_out;
    float* out_v = out_p + NN;

    const int NB_N   = (NN + 255) / 256;  // 391
    const int NB_E   = (NE + 255) / 256;  // 6250
    const int NB_NOD = NN / 8;            // 12500 (exact)

    // --- CSR build ---
    hipMemsetAsync(deg, 0, NN * sizeof(int), stream);
    hist_k<<<NB_E, 256, 0, stream>>>(dstA, deg);
    block_sum_k<<<NB_N, 256, 0, stream>>>(deg, bsum);
    scan_bsum_k<<<1, 512, 0, stream>>>(bsum, NB_N, ebase);
    scan_write_k<<<NB_N, 256, 0, stream>>>(deg, ebase, off, cursor);
    fill_k<<<NB_E, 256, 0, stream>>>(srcA, dstA, ew, cursor, csr);

    // --- Layer 1 ---
    matmul_k<64><<<NB_NOD, 256, 0, stream>>>(x, Win_rel, A);
    agg_root_relu_k<64><<<NB_NOD, 256, 0, stream>>>(A, x, Win_root, bin_rel,
                                                    csr, off, deg, H);
    // --- Layer 2 + heads ---
    matmul_k<32><<<NB_NOD, 256, 0, stream>>>(H, Wh_rel, A);
    agg2_heads_k<<<NB_NOD, 256, 0, stream>>>(A, H, Wh_root, bh_rel, Wp_rel,
                                             Wp_root, bp, Wv_rel, Wv_root, bv,
                                             csr, off, deg, pv, pbase, vbase);
    // --- Head aggregation + mask + finalize ---
    heads_final_k<<<NB_N, 256, 0, stream>>>(pv, pbase, vbase, csr, off, deg,
                                            cur, pm, out_v, parts);
    reduce_max_k<<<1, 256, 0, stream>>>(parts, NB_N, scal);
    expsum_k<<<NB_N, 256, 0, stream>>>(pm, scal, ev);
    normalize_k<<<NB_N, 256, 0, stream>>>(ev, scal, out_p);
}

// Round 3
// 451.207 us; speedup vs baseline: 1.5514x; 1.1010x over previous
//
#include <hip/hip_runtime.h>
#include <cmath>

static constexpr int NN = 100000;   // nodes
static constexpr int NE = 1600000;  // edges
static const size_t NW = (size_t)NN * 32;
static constexpr int NSLICE = 8;            // dst slices ~ XCDs
static constexpr int SLICE_W = 12500;       // NN / NSLICE
static constexpr int FILL_BPG = 256;        // blocks per slice group

// ---------------------------------------------------------------------------
// CSR build: histogram of dst, exclusive scan, XCD-sliced fill.
// ---------------------------------------------------------------------------
__global__ void __launch_bounds__(256) hist_k(const int* __restrict__ dst,
                                              int* __restrict__ deg)
{
    unsigned e = blockIdx.x * 256u + threadIdx.x;
    if (e < (unsigned)NE) atomicAdd(deg + dst[e], 1);
}

__global__ void __launch_bounds__(256) block_sum_k(const int* __restrict__ deg,
                                                   int* __restrict__ bsum)
{
    int n = blockIdx.x * 256 + threadIdx.x;
    int d = (n < NN) ? deg[n] : 0;
#pragma unroll
    for (int k = 32; k; k >>= 1) d += __shfl_xor(d, k, 64);
    __shared__ int s[4];
    if ((threadIdx.x & 63) == 0) s[threadIdx.x >> 6] = d;
    __syncthreads();
    if (threadIdx.x == 0) bsum[blockIdx.x] = s[0] + s[1] + s[2] + s[3];
}

__global__ void __launch_bounds__(512) scan_bsum_k(const int* __restrict__ bsum,
                                                   int np, int* __restrict__ ebase)
{
    __shared__ int tmp[512];
    int t = threadIdx.x;
    int v = (t < np) ? bsum[t] : 0;
    tmp[t] = v;
    __syncthreads();
    for (int s = 1; s < 512; s <<= 1) {
        int x = tmp[t];
        int add = (t >= s) ? tmp[t - s] : 0;
        __syncthreads();
        tmp[t] = x + add;
        __syncthreads();
    }
    if (t < np) ebase[t] = tmp[t] - v;
}

__global__ void __launch_bounds__(256) scan_write_k(const int* __restrict__ deg,
                                                    const int* __restrict__ ebase,
                                                    int* __restrict__ off,
                                                    int* __restrict__ cursor)
{
    __shared__ int tmp[256];
    int t = threadIdx.x;
    int n = blockIdx.x * 256 + t;
    int d = (n < NN) ? deg[n] : 0;
    tmp[t] = d;
    __syncthreads();
    for (int s = 1; s < 256; s <<= 1) {
        int x = tmp[t];
        int add = (t >= s) ? tmp[t - s] : 0;
        __syncthreads();
        tmp[t] = x + add;
        __syncthreads();
    }
    int excl = tmp[t] - d;
    if (n < NN) {
        int base = ebase[blockIdx.x] + excl;
        off[n] = base;
        cursor[n] = base;
    }
}

// XCD-sliced fill: group g (= blockIdx%8, dispatch round-robin ~ one XCD)
// writes only csr entries for dst in [g*12500,(g+1)*12500). Each csr line is
// then dirty in a single XCD's L2 -> one full-line write-back instead of 8
// partial ones. Extra cost: each group streams the whole dst array.
__global__ void __launch_bounds__(256) fill2_k(const int* __restrict__ src,
                                               const int* __restrict__ dst,
                                               const float* __restrict__ ew,
                                               int* __restrict__ cursor,
                                               int2* __restrict__ csr)
{
    int g = blockIdx.x & (NSLICE - 1);
    int b = blockIdx.x >> 3;
    int lo = g * SLICE_W, hi = lo + SLICE_W;
    for (int e = b * 256 + (int)threadIdx.x; e < NE; e += FILL_BPG * 256) {
        int d = dst[e];
        if (d < lo || d >= hi) continue;
        int pos = atomicAdd(cursor + d, 1);
        int2 pk;
        pk.x = src[e];
        pk.y = __float_as_int(ew[e]);
        csr[pos] = pk;
    }
}

// ---------------------------------------------------------------------------
// proj = in @ W  (W: [K,32] in LDS). 8 nodes/block, lane j owns col j.
// ---------------------------------------------------------------------------
template <int K>
__global__ void __launch_bounds__(256) matmul_k(const float* __restrict__ in,
                                                const float* __restrict__ W,
                                                float* __restrict__ out)
{
    __shared__ float sW[K * 32];
    for (int i = threadIdx.x; i < K * 32; i += 256) sW[i] = W[i];
    __syncthreads();
    int n = blockIdx.x * 8 + (threadIdx.x >> 5);
    int j = threadIdx.x & 31;
    const float* row = in + (size_t)n * K;
    float acc = 0.f;
#pragma unroll
    for (int k = 0; k < K; ++k) acc = fmaf(row[k], sW[k * 32 + j], acc);
    out[(size_t)n * 32 + j] = acc;
}

// ---------------------------------------------------------------------------
// Gather-aggregate layer: h_out[n] = relu( sum_e w_e*proj[src_e] + b + x@Wroot )
// ---------------------------------------------------------------------------
template <int K>
__global__ void __launch_bounds__(256) agg_root_relu_k(
    const float* __restrict__ proj, const float* __restrict__ xin,
    const float* __restrict__ Wroot, const float* __restrict__ bias,
    const int2* __restrict__ csr, const int* __restrict__ off,
    const int* __restrict__ deg, float* __restrict__ hout)
{
    __shared__ float sW[K * 32];
    for (int i = threadIdx.x; i < K * 32; i += 256) sW[i] = Wroot[i];
    __syncthreads();
    int n = blockIdx.x * 8 + (threadIdx.x >> 5);
    int j = threadIdx.x & 31;
    int st = off[n], dg = deg[n];
    float acc = 0.f;
    int i = 0;
    for (; i + 3 < dg; i += 4) {
        int2 e0 = csr[st + i], e1 = csr[st + i + 1];
        int2 e2 = csr[st + i + 2], e3 = csr[st + i + 3];
        float a0 = proj[(size_t)e0.x * 32 + j];
        float a1 = proj[(size_t)e1.x * 32 + j];
        float a2 = proj[(size_t)e2.x * 32 + j];
        float a3 = proj[(size_t)e3.x * 32 + j];
        acc = fmaf(a0, __int_as_float(e0.y), acc);
        acc = fmaf(a1, __int_as_float(e1.y), acc);
        acc = fmaf(a2, __int_as_float(e2.y), acc);
        acc = fmaf(a3, __int_as_float(e3.y), acc);
    }
    for (; i < dg; ++i) {
        int2 e0 = csr[st + i];
        acc = fmaf(proj[(size_t)e0.x * 32 + j], __int_as_float(e0.y), acc);
    }
    const float* row = xin + (size_t)n * K;
    float r = 0.f;
#pragma unroll
    for (int k = 0; k < K; ++k) r = fmaf(row[k], sW[k * 32 + j], r);
    float v = acc + bias[j] + r;
    hout[(size_t)n * 32 + j] = v > 0.f ? v : 0.f;
}

// ---------------------------------------------------------------------------
// Layer-2 aggregate + inline root + ReLU + all four OUT=1 head projections.
// ---------------------------------------------------------------------------
__global__ void __launch_bounds__(256) agg2_heads_k(
    const float* __restrict__ proj, const float* __restrict__ h1,
    const float* __restrict__ Wroot, const float* __restrict__ bias,
    const float* __restrict__ Wp_rel, const float* __restrict__ Wp_root,
    const float* __restrict__ bp, const float* __restrict__ Wv_rel,
    const float* __restrict__ Wv_root, const float* __restrict__ bv,
    const int2* __restrict__ csr, const int* __restrict__ off,
    const int* __restrict__ deg, float2* __restrict__ pv,
    float* __restrict__ pbase, float* __restrict__ vbase)
{
    __shared__ float sW[32 * 32];
    __shared__ float sHead[4 * 32];
    for (int i = threadIdx.x; i < 32 * 32; i += 256) sW[i] = Wroot[i];
    if (threadIdx.x < 32) {
        sHead[threadIdx.x] = Wp_rel[threadIdx.x];
        sHead[32 + threadIdx.x] = Wp_root[threadIdx.x];
        sHead[64 + threadIdx.x] = Wv_rel[threadIdx.x];
        sHead[96 + threadIdx.x] = Wv_root[threadIdx.x];
    }
    __syncthreads();
    int n = blockIdx.x * 8 + (threadIdx.x >> 5);
    int j = threadIdx.x & 31;
    int st = off[n], dg = deg[n];
    float acc = 0.f;
    int i = 0;
    for (; i + 3 < dg; i += 4) {
        int2 e0 = csr[st + i], e1 = csr[st + i + 1];
        int2 e2 = csr[st + i + 2], e3 = csr[st + i + 3];
        float a0 = proj[(size_t)e0.x * 32 + j];
        float a1 = proj[(size_t)e1.x * 32 + j];
        float a2 = proj[(size_t)e2.x * 32 + j];
        float a3 = proj[(size_t)e3.x * 32 + j];
        acc = fmaf(a0, __int_as_float(e0.y), acc);
        acc = fmaf(a1, __int_as_float(e1.y), acc);
        acc = fmaf(a2, __int_as_float(e2.y), acc);
        acc = fmaf(a3, __int_as_float(e3.y), acc);
    }
    for (; i < dg; ++i) {
        int2 e0 = csr[st + i];
        acc = fmaf(proj[(size_t)e0.x * 32 + j], __int_as_float(e0.y), acc);
    }
    const float* row = h1 + (size_t)n * 32;
    float r = 0.f;
#pragma unroll
    for (int k = 0; k < 32; ++k) r = fmaf(row[k], sW[k * 32 + j], r);
    float hv = acc + bias[j] + r;
    hv = hv > 0.f ? hv : 0.f;
    float prv = hv * sHead[j];
    float pov = hv * sHead[32 + j];
    float vrv = hv * sHead[64 + j];
    float vov = hv * sHead[96 + j];
#pragma unroll
    for (int m = 16; m; m >>= 1) {
        prv += __shfl_xor(prv, m, 32);
        pov += __shfl_xor(pov, m, 32);
        vrv += __shfl_xor(vrv, m, 32);
        vov += __shfl_xor(vov, m, 32);
    }
    if (j == 0) {
        pv[n] = make_float2(prv, vrv);
        pbase[n] = pov + bp[0];
        vbase[n] = vov + bv[0];
    }
}

// ---------------------------------------------------------------------------
// Per-node head aggregation + legal-move mask + masked outputs + block max.
// ---------------------------------------------------------------------------
__global__ void __launch_bounds__(256) heads_final_k(
    const float2* __restrict__ pv, const float* __restrict__ pbase,
    const float* __restrict__ vbase, const int2* __restrict__ csr,
    const int* __restrict__ off, const int* __restrict__ deg,
    const int* __restrict__ curp, float* __restrict__ pm,
    float* __restrict__ out_v, float* __restrict__ partials)
{
    int n = blockIdx.x * 256 + threadIdx.x;
    int cur = curp[0];
    float pmv = -INFINITY;
    if (n < NN) {
        int st = off[n], dg = deg[n];
        float pa = 0.f, va = 0.f, m = 0.f;
        for (int i = 0; i < dg; ++i) {
            int2 e = csr[st + i];
            float2 t = pv[e.x];
            float w = __int_as_float(e.y);
            pa = fmaf(t.x, w, pa);
            va = fmaf(t.y, w, va);
            if (e.x == cur) m = 1.f;
        }
        float p = pa + pbase[n];
        float v = va + vbase[n];
        float pm0 = m * p;
        pmv = (pm0 == 0.f) ? -INFINITY : pm0;  // jnp.where(p_m==0, -inf, p_m)
        pm[n] = pmv;
        out_v[n] = m * v;
    }
    __shared__ float smax[4];
    float wm = pmv;
#pragma unroll
    for (int k = 32; k; k >>= 1) wm = fmaxf(wm, __shfl_xor(wm, k, 64));
    if ((threadIdx.x & 63) == 0) smax[threadIdx.x >> 6] = wm;
    __syncthreads();
    if (threadIdx.x == 0)
        partials[blockIdx.x] = fmaxf(fmaxf(smax[0], smax[1]), fmaxf(smax[2], smax[3]));
}

__global__ void __launch_bounds__(256) reduce_max_k(
    const float* __restrict__ partials, int np, float* __restrict__ scal)
{
    float m = -INFINITY;
    for (int i = threadIdx.x; i < np; i += 256) m = fmaxf(m, partials[i]);
    __shared__ float s[4];
#pragma unroll
    for (int k = 32; k; k >>= 1) m = fmaxf(m, __shfl_xor(m, k, 64));
    if ((threadIdx.x & 63) == 0) s[threadIdx.x >> 6] = m;
    __syncthreads();
    if (threadIdx.x == 0) {
        scal[0] = fmaxf(fmaxf(s[0], s[1]), fmaxf(s[2], s[3]));
        scal[1] = 0.f;
    }
}

__global__ void __launch_bounds__(256) expsum_k(const float* __restrict__ pm,
                                                float* __restrict__ scal,
                                                float* __restrict__ ev)
{
    int n = blockIdx.x * 256 + threadIdx.x;
    float e = 0.f;
    if (n < NN) {
        float x = pm[n];
        e = (x == -INFINITY) ? 0.f : expf(x - scal[0]);
        ev[n] = e;
    }
    __shared__ float s[4];
    float ws = e;
#pragma unroll
    for (int k = 32; k; k >>= 1) ws += __shfl_xor(ws, k, 64);
    if ((threadIdx.x & 63) == 0) s[threadIdx.x >> 6] = ws;
    __syncthreads();
    if (threadIdx.x == 0) atomicAdd(scal + 1, s[0] + s[1] + s[2] + s[3]);
}

__global__ void __launch_bounds__(256) normalize_k(const float* __restrict__ ev,
                                                   const float* __restrict__ scal,
                                                   float* __restrict__ out)
{
    int n = blockIdx.x * 256 + threadIdx.x;
    if (n < NN) out[n] = ev[n] / scal[1];
}

// ---------------------------------------------------------------------------
extern "C" void kernel_launch(void* const* d_in, const int* in_sizes, int n_in,
                              void* d_out, int out_size, void* d_ws,
                              size_t ws_size, hipStream_t stream)
{
    const float* x        = (const float*)d_in[0];
    const int*   ei       = (const int*)d_in[1];   // [2,E] row-major
    const float* ew       = (const float*)d_in[2];
    const int*   cur      = (const int*)d_in[3];
    const float* Win_rel  = (const float*)d_in[4];
    const float* bin_rel  = (const float*)d_in[5];
    const float* Win_root = (const float*)d_in[6];
    const float* Wh_rel   = (const float*)d_in[7];
    const float* bh_rel   = (const float*)d_in[8];
    const float* Wh_root  = (const float*)d_in[9];
    const float* Wp_rel   = (const float*)d_in[10];
    const float* bp       = (const float*)d_in[11];
    const float* Wp_root  = (const float*)d_in[12];
    const float* Wv_rel   = (const float*)d_in[13];
    const float* bv       = (const float*)d_in[14];
    const float* Wv_root  = (const float*)d_in[15];

    const int* srcA = ei;
    const int* dstA = ei + NE;

    char* w8 = (char*)d_ws;
    int2* csr   = (int2*)w8;                 // 12.8 MB
    int* deg    = (int*)(csr + NE);          // 400 KB
    int* off    = deg + NN;
    int* cursor = off + NN;
    int* bsum   = cursor + NN;               // 512 ints
    int* ebase  = bsum + 512;                // 512 ints
    float* A    = (float*)(ebase + 512);     // 12.8 MB  (proj1 / proj2)
    float* H    = A + NW;                    // 12.8 MB  (h1)
    float2* pv  = (float2*)(H + NW);         // 800 KB
    float* pbase = (float*)(pv + NN);        // 400 KB
    float* vbase = pbase + NN;               // 400 KB
    // aliases into A (free after agg2_heads_k):
    float* pm    = A;
    float* ev    = A + NN;
    float* parts = A + 2 * (size_t)NN;       // 391
    float* scal  = parts + 512;

    float* out_p = (float*)d_out;
    float* out_v = out_p + NN;

    const int NB_N   = (NN + 255) / 256;  // 391
    const int NB_E   = (NE + 255) / 256;  // 6250
    const int NB_NOD = NN / 8;            // 12500 (exact)

    // --- CSR build ---
    hipMemsetAsync(deg, 0, NN * sizeof(int), stream);
    hist_k<<<NB_E, 256, 0, stream>>>(dstA, deg);
    block_sum_k<<<NB_N, 256, 0, stream>>>(deg, bsum);
    scan_bsum_k<<<1, 512, 0, stream>>>(bsum, NB_N, ebase);
    scan_write_k<<<NB_N, 256, 0, stream>>>(deg, ebase, off, cursor);
    fill2_k<<<NSLICE * FILL_BPG, 256, 0, stream>>>(srcA, dstA, ew, cursor, csr);

    // --- Layer 1 ---
    matmul_k<64><<<NB_NOD, 256, 0, stream>>>(x, Win_rel, A);
    agg_root_relu_k<64><<<NB_NOD, 256, 0, stream>>>(A, x, Win_root, bin_rel,
                                                    csr, off, deg, H);
    // --- Layer 2 + heads ---
    matmul_k<32><<<NB_NOD, 256, 0, stream>>>(H, Wh_rel, A);
    agg2_heads_k<<<NB_NOD, 256, 0, stream>>>(A, H, Wh_root, bh_rel, Wp_rel,
                                             Wp_root, bp, Wv_rel, Wv_root, bv,
                                             csr, off, deg, pv, pbase, vbase);
    // --- Head aggregation + mask + finalize ---
    heads_final_k<<<NB_N, 256, 0, stream>>>(pv, pbase, vbase, csr, off, deg,
                                            cur, pm, out_v, parts);
    reduce_max_k<<<1, 256, 0, stream>>>(parts, NB_N, scal);
    expsum_k<<<NB_N, 256, 0, stream>>>(pm, scal, ev);
    normalize_k<<<NB_N, 256, 0, stream>>>(ev, scal, out_p);
}